// Round 5
// baseline (308.565 us; speedup 1.0000x reference)
//
#include <hip/hip_runtime.h>
#include <math.h>

#define B_     8
#define C_H_   128
#define C_L_   256
#define K_     64
#define NPIX_L 16384          // 128*128
#define EPS_   1e-5f

// ws layout: P (float) | B1 (bf16, swizzled) | B2 (bf16, swizzled) | bias (float)
#define P_OFF     0
#define P_SZ      (B_*K_*C_H_)                 // 65536 floats
#define B1_BYTE   (P_SZ*4)                     // 262144
#define B2_BYTE   (B1_BYTE + B_*K_*C_L_*2)     // +262144
#define BIAS_BYTE (B2_BYTE + B_*K_*C_L_*2)     // 512 floats

typedef short bf16x8 __attribute__((ext_vector_type(8)));   // 4 VGPRs = 8 bf16
typedef float f32x4  __attribute__((ext_vector_type(4)));

__device__ inline unsigned short f2bf(float f) {            // RNE fp32->bf16
    unsigned int u = __float_as_uint(f);
    u += 0x7FFFu + ((u >> 16) & 1u);
    return (unsigned short)(u >> 16);
}
__device__ inline unsigned int pack2bf(float lo, float hi) { // two bf16 in one u32
    unsigned int ul = __float_as_uint(lo);
    unsigned int uh = __float_as_uint(hi);
    ul = (ul + (0x7FFFu + ((ul >> 16) & 1u))) >> 16;
    uh = (uh + (0x7FFFu + ((uh >> 16) & 1u))) & 0xFFFF0000u;
    return ul | uh;
}

#define MFMA16(a, b, c) __builtin_amdgcn_mfma_f32_16x16x32_bf16((a), (b), (c), 0, 0, 0)

#define GLOAD_LDS16(g, l) __builtin_amdgcn_global_load_lds( \
    (const __attribute__((address_space(1))) void*)(g), \
    (__attribute__((address_space(3))) void*)(l), 16, 0, 0)

// ---------------- Kernel 1: BN + 8x8 max-pool of x_h -> p[b][k][c] ----------------
__global__ __launch_bounds__(256) void pool_bn_kernel(
    const float* __restrict__ x_h,
    const float* __restrict__ g, const float* __restrict__ be,
    const float* __restrict__ mn, const float* __restrict__ vr,
    float* __restrict__ ws)
{
    const int t   = threadIdx.x;
    const int k   = t & 63;
    const int cl  = t >> 6;
    const int bid = blockIdx.x;    // 256 = 8 b * 32 cgroups
    const int b   = bid >> 5;
    const int c   = ((bid & 31) << 2) + cl;

    const float* plane = x_h + ((size_t)(b * C_H_ + c) << 12);
    const int ph = k >> 3, pw = k & 7;
    const float* p0 = plane + (ph * 8) * 64 + pw * 8;

    float mx = -INFINITY, mnv = INFINITY;
#pragma unroll
    for (int i = 0; i < 8; i++) {
        const float4 a  = *reinterpret_cast<const float4*>(p0 + i * 64);
        const float4 bq = *reinterpret_cast<const float4*>(p0 + i * 64 + 4);
        mx  = fmaxf(mx,  fmaxf(fmaxf(a.x, a.y),  fmaxf(a.z, a.w)));
        mx  = fmaxf(mx,  fmaxf(fmaxf(bq.x, bq.y), fmaxf(bq.z, bq.w)));
        mnv = fminf(mnv, fminf(fminf(a.x, a.y),  fminf(a.z, a.w)));
        mnv = fminf(mnv, fminf(fminf(bq.x, bq.y), fminf(bq.z, bq.w)));
    }
    const float sc  = g[c] * rsqrtf(vr[c] + EPS_);
    const float sel = (sc >= 0.f) ? mx : mnv;
    ws[P_OFF + (b * K_ + k) * C_H_ + c] = fmaf(sel - mn[c], sc, be[c]);
}

// ---------------- Kernel 2: kv projection (coalesced, R4 version) ----------------
__global__ __launch_bounds__(256) void kv_kernel(
    const float* __restrict__ kv_w, const float* __restrict__ kv_b,
    const float* __restrict__ lg, const float* __restrict__ lb,
    const float* __restrict__ lm, const float* __restrict__ lv,
    const float* __restrict__ ratt,
    float* __restrict__ ws)
{
    __shared__ __align__(16) float plds[4 * 132];
    __shared__ float red[4][4];
    const int t    = threadIdx.x;
    const int lane = t & 63;
    const int wid  = t >> 6;
    const int bid  = blockIdx.x;        // 256 = b(8) * kg(16) * oh(2)
    const int b    = bid >> 5;
    const int kg   = (bid >> 1) & 15;
    const int oh   = bid & 1;

    if (t < 128) {                       // stage p: 4 rows x 128 floats
        const int px = t >> 5, u = t & 31;
        const float4 v = *reinterpret_cast<const float4*>(
            ws + P_OFF + (size_t)(b * K_ + kg * 4 + px) * C_H_ + u * 4);
        *reinterpret_cast<float4*>(plds + px * 132 + u * 4) = v;
    }
    __syncthreads();

    const int oi = t >> 2;               // 0..63
    const int q4 = t & 3;
    const int kk = kg * 4 + q4;

    unsigned short* b1 = (unsigned short*)((char*)ws + B1_BYTE);
    unsigned short* b2 = (unsigned short*)((char*)ws + B2_BYTE);

    float bc = 0.f;
#pragma unroll
    for (int pass = 0; pass < 4; pass++) {
        const int o = oh * 256 + pass * 64 + oi;
        const float* wrow = kv_w + (size_t)o * C_H_ + q4 * 4;
        float a0 = 0.f, a1 = 0.f, a2 = 0.f, a3 = 0.f;
#pragma unroll
        for (int i = 0; i < 8; i++) {
            const float4 wf = *reinterpret_cast<const float4*>(wrow + i * 16);
            const float4 p0 = *reinterpret_cast<const float4*>(plds + 0 * 132 + i * 16 + q4 * 4);
            const float4 p1 = *reinterpret_cast<const float4*>(plds + 1 * 132 + i * 16 + q4 * 4);
            const float4 p2 = *reinterpret_cast<const float4*>(plds + 2 * 132 + i * 16 + q4 * 4);
            const float4 p3 = *reinterpret_cast<const float4*>(plds + 3 * 132 + i * 16 + q4 * 4);
            a0 = fmaf(wf.x, p0.x, a0); a0 = fmaf(wf.y, p0.y, a0);
            a0 = fmaf(wf.z, p0.z, a0); a0 = fmaf(wf.w, p0.w, a0);
            a1 = fmaf(wf.x, p1.x, a1); a1 = fmaf(wf.y, p1.y, a1);
            a1 = fmaf(wf.z, p1.z, a1); a1 = fmaf(wf.w, p1.w, a1);
            a2 = fmaf(wf.x, p2.x, a2); a2 = fmaf(wf.y, p2.y, a2);
            a2 = fmaf(wf.z, p2.z, a2); a2 = fmaf(wf.w, p2.w, a2);
            a3 = fmaf(wf.x, p3.x, a3); a3 = fmaf(wf.y, p3.y, a3);
            a3 = fmaf(wf.z, p3.z, a3); a3 = fmaf(wf.w, p3.w, a3);
        }
        a0 += __shfl_xor(a0, 1, 64); a0 += __shfl_xor(a0, 2, 64);
        a1 += __shfl_xor(a1, 1, 64); a1 += __shfl_xor(a1, 2, 64);
        a2 += __shfl_xor(a2, 1, 64); a2 += __shfl_xor(a2, 2, 64);
        a3 += __shfl_xor(a3, 1, 64); a3 += __shfl_xor(a3, 2, 64);
        float val = (q4 == 0) ? a0 : (q4 == 1) ? a1 : (q4 == 2) ? a2 : a3;
        val += kv_b[o];

        if (oh == 0) {   // ck path
            const float s = lg[o] * rsqrtf(lv[o] + EPS_);
            const float h = fmaf(-lm[o], s, lb[o]);
            bc = fmaf(h, val, bc);
            const int s1 = o >> 5, j = o & 7;
            const int l  = ((o >> 3) & 3) * 16 + (kk & 15);
            const int n  = kk >> 4;
            b1[((((b * 8 + s1) * 4 + n) * 64) + l) * 8 + j] = f2bf(val * s);
        } else {         // cv path
            const int co = o - 256;
            const int s2 = kk >> 5, j2 = kk & 7;
            const int l2 = ((kk >> 3) & 3) * 16 + (co & 15);
            const int n2 = co >> 4;
            b2[((((b * 2 + s2) * 16 + n2) * 64) + l2) * 8 + j2] = f2bf(val);
        }
    }

    if (oh == 0) {
#pragma unroll
        for (int m = 4; m < 64; m <<= 1) bc += __shfl_xor(bc, m, 64);
        if (lane < 4) red[wid][lane] = bc;
        __syncthreads();
        if (t < 4) {
            const float sum = red[0][t] + red[1][t] + red[2][t] + red[3][t];
            const int kkf = kg * 4 + t;
            float* bia = (float*)((char*)ws + BIAS_BYTE);
            bia[b * K_ + kkf] = (sum + ratt[kkf]) * 0.125f;
        }
    }
}

// ---------------- Kernel 3: MFMA attention (pipelined B1 + 64px blocks) ----------------
// 2048 blocks (b=bid&7), 256 threads = 4 waves, 64 px/block, 16 px/wave.
// Fixes vs R4: (1) B1 frags software-pipelined one K-step ahead so the
// counted vmcnt(2) never has to drain the stage prefetch (in-order vmcnt:
// stage(s) < b1(s) < stage(s+1)); (2) 6 blocks/CU (launch_bounds(256,6),
// LDS 17.9KB) -> 24 waves/CU vs 16.
// Swizzle: stage global unit ^ ((wid&1)<<2); read col ^ ((q&1)<<4) -> 2-way banks.
__global__ __launch_bounds__(256, 6) void attn_mfma(
    const float* __restrict__ x_l,
    const float* __restrict__ ws_f,
    float* __restrict__ out)
{
    // [0,8192) xbuf0 | [8192,16384) xbuf1 ; after GEMM1:
    //   obuf [0,8704) = 32co x 68 floats ; wscr [8704,17920) = 4 x 16row x 72 shorts
    __shared__ __align__(16) char lds[17920];
    float* xbuf0 = (float*)lds;
    float* xbuf1 = (float*)(lds + 8192);
    float* obuf  = (float*)lds;
    unsigned short* wscr = (unsigned short*)(lds + 8704);

    const int t    = threadIdx.x;
    const int lane = t & 63;
    const int wid  = t >> 6;                  // 0..3
    const int bid  = blockIdx.x;
    const int b    = bid & 7;
    const int tile = bid >> 3;                // 0..255
    const int px0  = tile * 64;               // block pixel base
    const int r16  = lane & 15;
    const int q    = lane >> 4;

    const unsigned short* b1 = (const unsigned short*)((const char*)ws_f + B1_BYTE);
    const unsigned short* b2 = (const unsigned short*)((const char*)ws_f + B2_BYTE);
    const float* biasf = (const float*)((const char*)ws_f + BIAS_BYTE) + b * K_;
    const float* xb = x_l + (size_t)b * (C_L_ * NPIX_L);
    float* ob = out + (size_t)b * (C_L_ * NPIX_L);

    float bl[4];
#pragma unroll
    for (int n = 0; n < 4; n++) bl[n] = biasf[16 * n + r16];

    // staging: wave stages rows cl = 8*wid+4*i_+sd (sd=lane>>4), 4 rows/call
    // (64 lanes x 16B = 1KB = 4 rows of 256B). Global float offset pre-XORed
    // by ((wid&1)<<4) so frag reads hit <=2-way banks; LDS stays linear.
    const int sd = lane >> 4;
    const int su = ((lane & 15) << 2) ^ ((wid & 1) << 4);
#define STAGE(bufp, s_) do { \
    _Pragma("unroll") \
    for (int i_ = 0; i_ < 2; i_++) { \
        const int cl_ = 8 * wid + 4 * i_; \
        const float* gp_ = xb + (size_t)(32 * (s_) + cl_ + sd) * NPIX_L + px0 + su; \
        GLOAD_LDS16(gp_, (bufp) + (size_t)cl_ * 64); \
    } \
} while (0)

    // ---- GEMM1: dbuf staging + B1 frags pipelined one step ahead ----
    f32x4 acc1[4] = {};
    union ABu { bf16x8 v; unsigned int u[4]; };
    bf16x8 bfr[2][4];
    const bf16x8* bbase = ((const bf16x8*)b1) + (b * 8 * 4) * 64 + lane;

    STAGE(xbuf0, 0);
#pragma unroll
    for (int n = 0; n < 4; n++) bfr[0][n] = bbase[n * 64];

    const int p0x = (wid * 16 + r16) ^ ((q & 1) << 4);   // swizzled LDS col

#pragma unroll
    for (int s = 0; s < 8; s++) {
        const int p = s & 1;
        float* xbf = p ? xbuf1 : xbuf0;
        if (s < 7) {
            STAGE(p ? xbuf0 : xbuf1, s + 1);
            asm volatile("s_waitcnt vmcnt(2)" ::: "memory");  // drain stage(s)+b1(s); stage(s+1) flies
        } else {
            asm volatile("s_waitcnt vmcnt(0)" ::: "memory");
        }
        __builtin_amdgcn_s_barrier();   // chunk s visible block-wide

        if (s < 7) {                    // prefetch next step's B1 frags (hidden under compute)
#pragma unroll
            for (int n = 0; n < 4; n++) bfr[p ^ 1][n] = bbase[((s + 1) * 4 + n) * 64];
        }

        ABu a0f;
#pragma unroll
        for (int jj = 0; jj < 4; jj++) {
            const float* row0 = xbf + (8 * q + 2 * jj) * 64;
            a0f.u[jj] = pack2bf(row0[p0x], row0[64 + p0x]);
        }
#pragma unroll
        for (int n = 0; n < 4; n++) acc1[n] = MFMA16(a0f.v, bfr[p][n], acc1[n]);
        __builtin_amdgcn_s_barrier();   // all waves done with buf before overwrite
    }

    // ---- softmax (px = 4q+r local, kk = 16n+r16) + W -> per-wave scratch ----
    unsigned short* wsb = wscr + wid * 1152;   // 16 rows x 72 shorts
#pragma unroll
    for (int r = 0; r < 4; r++) {
        float e0 = fmaf(acc1[0][r], 0.125f, bl[0]);
        float e1 = fmaf(acc1[1][r], 0.125f, bl[1]);
        float e2 = fmaf(acc1[2][r], 0.125f, bl[2]);
        float e3 = fmaf(acc1[3][r], 0.125f, bl[3]);
        float mx = fmaxf(fmaxf(e0, e1), fmaxf(e2, e3));
#pragma unroll
        for (int msk = 1; msk < 16; msk <<= 1) mx = fmaxf(mx, __shfl_xor(mx, msk, 64));
        e0 = __expf(e0 - mx); e1 = __expf(e1 - mx);
        e2 = __expf(e2 - mx); e3 = __expf(e3 - mx);
        float sm = (e0 + e1) + (e2 + e3);
#pragma unroll
        for (int msk = 1; msk < 16; msk <<= 1) sm += __shfl_xor(sm, msk, 64);
        const float inv = 1.f / sm;
        unsigned short* wp = wsb + (q * 4 + r) * 72 + r16;
        wp[0]  = f2bf(e0 * inv);
        wp[16] = f2bf(e1 * inv);
        wp[32] = f2bf(e2 * inv);
        wp[48] = f2bf(e3 * inv);
    }

    // ---- W A-frags from LDS (A[px=r16][kk = 32s + 8q + j]) ----
    bf16x8 af[2];
#pragma unroll
    for (int s2 = 0; s2 < 2; s2++)
        af[s2] = *(const bf16x8*)(wsb + r16 * 72 + 32 * s2 + q * 8);

    // ---- GEMM2 + LDS-transposed epilogue (8 chunks of 32 co) ----
#pragma unroll
    for (int nc = 0; nc < 8; nc++) {
        f32x4 acc2[2] = {};
#pragma unroll
        for (int s2 = 0; s2 < 2; s2++) {
            const bf16x8* bp2 = ((const bf16x8*)b2) + ((b * 2 + s2) * 16 + nc * 2) * 64 + lane;
#pragma unroll
            for (int nn = 0; nn < 2; nn++) {
                const bf16x8 bfr2 = bp2[nn * 64];
                acc2[nn] = MFMA16(af[s2], bfr2, acc2[nn]);
            }
        }
        // deposit: D[px=4q+r][co=16nn+r16] -> obuf[co][px]
#pragma unroll
        for (int nn = 0; nn < 2; nn++) {
            float* dp = obuf + (16 * nn + r16) * 68 + wid * 16 + 4 * q;
            *(f32x4*)dp = acc2[nn];
        }
        asm volatile("s_waitcnt lgkmcnt(0)" ::: "memory"); // own deposits done
        __builtin_amdgcn_s_barrier();
        const int cbase = nc * 32;
#pragma unroll
        for (int u2 = 0; u2 < 2; u2++) {
            const int idx = t + 256 * u2;      // 0..511
            const int col = idx >> 4;          // co_local 0..31
            const int un  = idx & 15;          // 16B-unit within 64px row
            const float4 vv = *(const float4*)(obuf + col * 68 + un * 4);
            const size_t gbase = (size_t)(cbase + col) * NPIX_L + px0 + un * 4;
            const float4 xv4 = *(const float4*)(xb + gbase);
            float4 o;
            o.x = vv.x + xv4.x; o.y = vv.y + xv4.y;
            o.z = vv.z + xv4.z; o.w = vv.w + xv4.w;
            *(float4*)(ob + gbase) = o;
        }
        __builtin_amdgcn_s_barrier();          // reads done before next deposit
    }
#undef STAGE
}

extern "C" void kernel_launch(void* const* d_in, const int* in_sizes, int n_in,
                              void* d_out, int out_size, void* d_ws, size_t ws_size,
                              hipStream_t stream) {
    const float* x_h  = (const float*)d_in[0];
    const float* x_l  = (const float*)d_in[1];
    const float* hg   = (const float*)d_in[2];
    const float* hb   = (const float*)d_in[3];
    const float* hm   = (const float*)d_in[4];
    const float* hv   = (const float*)d_in[5];
    const float* kvw  = (const float*)d_in[6];
    const float* kvb  = (const float*)d_in[7];
    const float* lg   = (const float*)d_in[8];
    const float* lb   = (const float*)d_in[9];
    const float* lm   = (const float*)d_in[10];
    const float* lv   = (const float*)d_in[11];
    const float* ratt = (const float*)d_in[12];
    float* ws  = (float*)d_ws;
    float* out = (float*)d_out;

    pool_bn_kernel<<<256, 256, 0, stream>>>(x_h, hg, hb, hm, hv, ws);
    kv_kernel<<<256, 256, 0, stream>>>(kvw, kvb, lg, lb, lm, lv, ratt, ws);
    attn_mfma<<<2048, 256, 0, stream>>>(x_l, ws, out);
}

// Round 6
// 294.266 us; speedup vs baseline: 1.0486x; 1.0486x over previous
//
#include <hip/hip_runtime.h>
#include <math.h>

#define B_     8
#define C_H_   128
#define C_L_   256
#define K_     64
#define NPIX_L 16384          // 128*128
#define EPS_   1e-5f

// ws layout: P (float) | B1 (bf16, swizzled) | B2 (bf16, swizzled) | bias (float)
#define P_OFF     0
#define P_SZ      (B_*K_*C_H_)                 // 65536 floats
#define B1_BYTE   (P_SZ*4)                     // 262144
#define B2_BYTE   (B1_BYTE + B_*K_*C_L_*2)     // +262144
#define BIAS_BYTE (B2_BYTE + B_*K_*C_L_*2)     // 512 floats

typedef short bf16x8 __attribute__((ext_vector_type(8)));   // 4 VGPRs = 8 bf16
typedef float f32x4  __attribute__((ext_vector_type(4)));

__device__ inline unsigned short f2bf(float f) {            // RNE fp32->bf16
    unsigned int u = __float_as_uint(f);
    u += 0x7FFFu + ((u >> 16) & 1u);
    return (unsigned short)(u >> 16);
}
__device__ inline unsigned int pack2bf(float lo, float hi) { // two bf16 in one u32
    unsigned int ul = __float_as_uint(lo);
    unsigned int uh = __float_as_uint(hi);
    ul = (ul + (0x7FFFu + ((ul >> 16) & 1u))) >> 16;
    uh = (uh + (0x7FFFu + ((uh >> 16) & 1u))) & 0xFFFF0000u;
    return ul | uh;
}

#define MFMA16(a, b, c) __builtin_amdgcn_mfma_f32_16x16x32_bf16((a), (b), (c), 0, 0, 0)

#define GLOAD_LDS16(g, l) __builtin_amdgcn_global_load_lds( \
    (const __attribute__((address_space(1))) void*)(g), \
    (__attribute__((address_space(3))) void*)(l), 16, 0, 0)

// ---------------- Kernel 1: BN + 8x8 max-pool of x_h -> p[b][k][c] ----------------
__global__ __launch_bounds__(256) void pool_bn_kernel(
    const float* __restrict__ x_h,
    const float* __restrict__ g, const float* __restrict__ be,
    const float* __restrict__ mn, const float* __restrict__ vr,
    float* __restrict__ ws)
{
    const int t   = threadIdx.x;
    const int k   = t & 63;
    const int cl  = t >> 6;
    const int bid = blockIdx.x;    // 256 = 8 b * 32 cgroups
    const int b   = bid >> 5;
    const int c   = ((bid & 31) << 2) + cl;

    const float* plane = x_h + ((size_t)(b * C_H_ + c) << 12);
    const int ph = k >> 3, pw = k & 7;
    const float* p0 = plane + (ph * 8) * 64 + pw * 8;

    float mx = -INFINITY, mnv = INFINITY;
#pragma unroll
    for (int i = 0; i < 8; i++) {
        const float4 a  = *reinterpret_cast<const float4*>(p0 + i * 64);
        const float4 bq = *reinterpret_cast<const float4*>(p0 + i * 64 + 4);
        mx  = fmaxf(mx,  fmaxf(fmaxf(a.x, a.y),  fmaxf(a.z, a.w)));
        mx  = fmaxf(mx,  fmaxf(fmaxf(bq.x, bq.y), fmaxf(bq.z, bq.w)));
        mnv = fminf(mnv, fminf(fminf(a.x, a.y),  fminf(a.z, a.w)));
        mnv = fminf(mnv, fminf(fminf(bq.x, bq.y), fminf(bq.z, bq.w)));
    }
    const float sc  = g[c] * rsqrtf(vr[c] + EPS_);
    const float sel = (sc >= 0.f) ? mx : mnv;
    ws[P_OFF + (b * K_ + k) * C_H_ + c] = fmaf(sel - mn[c], sc, be[c]);
}

// ---------------- Kernel 2: kv projection (coalesced) ----------------
__global__ __launch_bounds__(256) void kv_kernel(
    const float* __restrict__ kv_w, const float* __restrict__ kv_b,
    const float* __restrict__ lg, const float* __restrict__ lb,
    const float* __restrict__ lm, const float* __restrict__ lv,
    const float* __restrict__ ratt,
    float* __restrict__ ws)
{
    __shared__ __align__(16) float plds[4 * 132];
    __shared__ float red[4][4];
    const int t    = threadIdx.x;
    const int lane = t & 63;
    const int wid  = t >> 6;
    const int bid  = blockIdx.x;        // 256 = b(8) * kg(16) * oh(2)
    const int b    = bid >> 5;
    const int kg   = (bid >> 1) & 15;
    const int oh   = bid & 1;

    if (t < 128) {                       // stage p: 4 rows x 128 floats
        const int px = t >> 5, u = t & 31;
        const float4 v = *reinterpret_cast<const float4*>(
            ws + P_OFF + (size_t)(b * K_ + kg * 4 + px) * C_H_ + u * 4);
        *reinterpret_cast<float4*>(plds + px * 132 + u * 4) = v;
    }
    __syncthreads();

    const int oi = t >> 2;               // 0..63
    const int q4 = t & 3;
    const int kk = kg * 4 + q4;

    unsigned short* b1 = (unsigned short*)((char*)ws + B1_BYTE);
    unsigned short* b2 = (unsigned short*)((char*)ws + B2_BYTE);

    float bc = 0.f;
#pragma unroll
    for (int pass = 0; pass < 4; pass++) {
        const int o = oh * 256 + pass * 64 + oi;
        const float* wrow = kv_w + (size_t)o * C_H_ + q4 * 4;
        float a0 = 0.f, a1 = 0.f, a2 = 0.f, a3 = 0.f;
#pragma unroll
        for (int i = 0; i < 8; i++) {
            const float4 wf = *reinterpret_cast<const float4*>(wrow + i * 16);
            const float4 p0 = *reinterpret_cast<const float4*>(plds + 0 * 132 + i * 16 + q4 * 4);
            const float4 p1 = *reinterpret_cast<const float4*>(plds + 1 * 132 + i * 16 + q4 * 4);
            const float4 p2 = *reinterpret_cast<const float4*>(plds + 2 * 132 + i * 16 + q4 * 4);
            const float4 p3 = *reinterpret_cast<const float4*>(plds + 3 * 132 + i * 16 + q4 * 4);
            a0 = fmaf(wf.x, p0.x, a0); a0 = fmaf(wf.y, p0.y, a0);
            a0 = fmaf(wf.z, p0.z, a0); a0 = fmaf(wf.w, p0.w, a0);
            a1 = fmaf(wf.x, p1.x, a1); a1 = fmaf(wf.y, p1.y, a1);
            a1 = fmaf(wf.z, p1.z, a1); a1 = fmaf(wf.w, p1.w, a1);
            a2 = fmaf(wf.x, p2.x, a2); a2 = fmaf(wf.y, p2.y, a2);
            a2 = fmaf(wf.z, p2.z, a2); a2 = fmaf(wf.w, p2.w, a2);
            a3 = fmaf(wf.x, p3.x, a3); a3 = fmaf(wf.y, p3.y, a3);
            a3 = fmaf(wf.z, p3.z, a3); a3 = fmaf(wf.w, p3.w, a3);
        }
        a0 += __shfl_xor(a0, 1, 64); a0 += __shfl_xor(a0, 2, 64);
        a1 += __shfl_xor(a1, 1, 64); a1 += __shfl_xor(a1, 2, 64);
        a2 += __shfl_xor(a2, 1, 64); a2 += __shfl_xor(a2, 2, 64);
        a3 += __shfl_xor(a3, 1, 64); a3 += __shfl_xor(a3, 2, 64);
        float val = (q4 == 0) ? a0 : (q4 == 1) ? a1 : (q4 == 2) ? a2 : a3;
        val += kv_b[o];

        if (oh == 0) {   // ck path
            const float s = lg[o] * rsqrtf(lv[o] + EPS_);
            const float h = fmaf(-lm[o], s, lb[o]);
            bc = fmaf(h, val, bc);
            const int s1 = o >> 5, j = o & 7;
            const int l  = ((o >> 3) & 3) * 16 + (kk & 15);
            const int n  = kk >> 4;
            b1[((((b * 8 + s1) * 4 + n) * 64) + l) * 8 + j] = f2bf(val * s);
        } else {         // cv path
            const int co = o - 256;
            const int s2 = kk >> 5, j2 = kk & 7;
            const int l2 = ((kk >> 3) & 3) * 16 + (co & 15);
            const int n2 = co >> 4;
            b2[((((b * 2 + s2) * 16 + n2) * 64) + l2) * 8 + j2] = f2bf(val);
        }
    }

    if (oh == 0) {
#pragma unroll
        for (int m = 4; m < 64; m <<= 1) bc += __shfl_xor(bc, m, 64);
        if (lane < 4) red[wid][lane] = bc;
        __syncthreads();
        if (t < 4) {
            const float sum = red[0][t] + red[1][t] + red[2][t] + red[3][t];
            const int kkf = kg * 4 + t;
            float* bia = (float*)((char*)ws + BIAS_BYTE);
            bia[b * K_ + kkf] = (sum + ratt[kkf]) * 0.125f;
        }
    }
}

// ---------------- Kernel 3: MFMA attention, full-HBM-row version ----------------
// 512 blocks = 64 tiles x 8 b (b=bid&7, XCD-pinned), 256 threads = 4 waves.
// 256 px/block, 64 px/wave (4 m-tiles). Every global request cluster is a full
// 1KB HBM row: GEMM1 stages 32c x 256px chunks (one gl_lds call = one 1KB
// channel row); epilogue stores/residual-reads 1KB co-rows. A whole 32KB chunk
// rides in flight during the dbuf stall (~64KB/CU outstanding, Little's law).
// Epilogue residual is depth-2 register-prefetched (rv ring, static-indexed).
__global__ __launch_bounds__(256, 2) void attn_mfma(
    const float* __restrict__ x_l,
    const float* __restrict__ ws_f,
    float* __restrict__ out)
{
    // [0,32768) xbuf0 | [32768,65536) xbuf1
    // after GEMM1: wscr [0,36864) = 4 waves x 64 rows x 72 shorts
    //              obuf [36864,70144) = 32 co x 260 floats
    __shared__ __align__(16) char lds[70144];
    float* xbuf0 = (float*)lds;
    float* xbuf1 = (float*)(lds + 32768);
    unsigned short* wscr = (unsigned short*)lds;
    float* obuf = (float*)(lds + 36864);

    const int t    = threadIdx.x;
    const int lane = t & 63;
    const int wid  = t >> 6;                  // 0..3
    const int bid  = blockIdx.x;
    const int b    = bid & 7;
    const int tile = bid >> 3;                // 0..63
    const int px0  = tile * 256;              // block pixel base
    const int r16  = lane & 15;
    const int q    = lane >> 4;

    const unsigned short* b1 = (const unsigned short*)((const char*)ws_f + B1_BYTE);
    const unsigned short* b2 = (const unsigned short*)((const char*)ws_f + B2_BYTE);
    const float* biasf = (const float*)((const char*)ws_f + BIAS_BYTE) + b * K_;
    const float* xb = x_l + (size_t)b * (C_L_ * NPIX_L);
    float* ob = out + (size_t)b * (C_L_ * NPIX_L);

    float bl[4];
#pragma unroll
    for (int n = 0; n < 4; n++) bl[n] = biasf[16 * n + r16];

    // staging: wave stages channel rows cl = 8*wid..8*wid+7; one call = one
    // full 1KB row (64 lanes x 16B). Global float offset pre-XORed by (wid<<4)
    // (16-float units) so frag reads land on 2-way banks; LDS stays linear.
    const int sof = (lane << 2) ^ (wid << 4);
#define STAGE(bufp, s_) do { \
    _Pragma("unroll") \
    for (int i_ = 0; i_ < 8; i_++) { \
        const int cl_ = 8 * wid + i_; \
        const float* gp_ = xb + (size_t)(32 * (s_) + cl_) * NPIX_L + px0 + sof; \
        GLOAD_LDS16(gp_, (bufp) + (size_t)cl_ * 256); \
    } \
} while (0)

    // ---- GEMM1: dbuf 32KB chunks + B1 frags pipelined one step ahead ----
    // vmcnt invariant: after wait_s only STAGE(s+1)[8] in flight (drains
    // STAGE(s)[8]+b1(s)[4] = 12 oldest of 20). Uniform vmcnt(8); last iter 0.
    f32x4 acc1[4][4] = {};
    union ABu { bf16x8 v; unsigned int u[4]; };
    bf16x8 bfr[2][4];
    const bf16x8* bbase = ((const bf16x8*)b1) + (b * 8 * 4) * 64 + lane;

    STAGE(xbuf0, 0);
#pragma unroll
    for (int n = 0; n < 4; n++) bfr[0][n] = bbase[n * 64];

#pragma unroll
    for (int s = 0; s < 8; s++) {
        const int p = s & 1;
        const float* xbf = p ? xbuf1 : xbuf0;
        if (s < 7) {
            STAGE(p ? xbuf0 : xbuf1, s + 1);
            asm volatile("s_waitcnt vmcnt(8)" ::: "memory");
        } else {
            asm volatile("s_waitcnt vmcnt(0)" ::: "memory");
        }
        __builtin_amdgcn_s_barrier();   // chunk s visible block-wide

        if (s < 7) {                    // prefetch next step's B1 frags
#pragma unroll
            for (int n = 0; n < 4; n++) bfr[p ^ 1][n] = bbase[((s + 1) * 4 + n) * 64];
        }

#pragma unroll
        for (int m = 0; m < 4; m++) {
            const int colm = (64 * wid + 16 * m + r16) ^ (q << 4);
            ABu amf;
#pragma unroll
            for (int jj = 0; jj < 4; jj++) {
                amf.u[jj] = pack2bf(xbf[(8 * q + 2 * jj) * 256 + colm],
                                    xbf[(8 * q + 2 * jj + 1) * 256 + colm]);
            }
#pragma unroll
            for (int n = 0; n < 4; n++)
                acc1[m][n] = MFMA16(amf.v, bfr[p][n], acc1[m][n]);
        }
        __builtin_amdgcn_s_barrier();   // all waves done with buf before overwrite
    }

    // ---- softmax (px = 64wid+16m+4q+r, kk = 16n+r16) + W -> per-wave scratch ----
    unsigned short* wsb = wscr + wid * (64 * 72);   // 64 rows x 72 shorts
#pragma unroll
    for (int m = 0; m < 4; m++) {
#pragma unroll
        for (int r = 0; r < 4; r++) {
            float e0 = fmaf(acc1[m][0][r], 0.125f, bl[0]);
            float e1 = fmaf(acc1[m][1][r], 0.125f, bl[1]);
            float e2 = fmaf(acc1[m][2][r], 0.125f, bl[2]);
            float e3 = fmaf(acc1[m][3][r], 0.125f, bl[3]);
            float mx = fmaxf(fmaxf(e0, e1), fmaxf(e2, e3));
#pragma unroll
            for (int msk = 1; msk < 16; msk <<= 1) mx = fmaxf(mx, __shfl_xor(mx, msk, 64));
            e0 = __expf(e0 - mx); e1 = __expf(e1 - mx);
            e2 = __expf(e2 - mx); e3 = __expf(e3 - mx);
            float sm = (e0 + e1) + (e2 + e3);
#pragma unroll
            for (int msk = 1; msk < 16; msk <<= 1) sm += __shfl_xor(sm, msk, 64);
            const float inv = 1.f / sm;
            unsigned short* wp = wsb + (16 * m + q * 4 + r) * 72 + r16;
            wp[0]  = f2bf(e0 * inv);
            wp[16] = f2bf(e1 * inv);
            wp[32] = f2bf(e2 * inv);
            wp[48] = f2bf(e3 * inv);
        }
    }

    // ---- W A-frags from LDS (A[px = 16m+r16][kk = 32s2 + 8q + j]) ----
    bf16x8 af[4][2];
#pragma unroll
    for (int m = 0; m < 4; m++)
#pragma unroll
        for (int s2 = 0; s2 < 2; s2++)
            af[m][s2] = *(const bf16x8*)(wsb + (16 * m + r16) * 72 + 32 * s2 + 8 * q);

    // ---- GEMM2 + epilogue: 8 chunks of 32 co; 1KB-row stores; depth-2
    //      register-prefetched residual (rv ring, all indices static). ----
    float4 rv[2][8];
#pragma unroll
    for (int u2 = 0; u2 < 8; u2++) {
        const int col = wid + 4 * u2;
        rv[0][u2] = *(const float4*)(xb + (size_t)col * NPIX_L + px0 + lane * 4);
    }
#pragma unroll
    for (int nc = 0; nc < 8; nc++) {
        f32x4 acc2[4][2] = {};
#pragma unroll
        for (int s2 = 0; s2 < 2; s2++) {
            const bf16x8* bp2 = ((const bf16x8*)b2) + ((b * 2 + s2) * 16 + nc * 2) * 64 + lane;
#pragma unroll
            for (int nn = 0; nn < 2; nn++) {
                const bf16x8 b2f = bp2[nn * 64];
#pragma unroll
                for (int m = 0; m < 4; m++)
                    acc2[m][nn] = MFMA16(af[m][s2], b2f, acc2[m][nn]);
            }
        }
        // deposit D[px=16m+4q+r][co=16nn+r16] -> obuf[co][64wid+16m+4q..+3]
#pragma unroll
        for (int m = 0; m < 4; m++)
#pragma unroll
            for (int nn = 0; nn < 2; nn++) {
                float* dp = obuf + (16 * nn + r16) * 260 + 64 * wid + 16 * m + 4 * q;
                *(f32x4*)dp = acc2[m][nn];
            }
        if (nc < 7) {   // prefetch next chunk's residual rows (full-chunk cover)
#pragma unroll
            for (int u2 = 0; u2 < 8; u2++) {
                const int col = wid + 4 * u2;
                rv[(nc + 1) & 1][u2] = *(const float4*)(
                    xb + (size_t)((nc + 1) * 32 + col) * NPIX_L + px0 + lane * 4);
            }
        }
        asm volatile("s_waitcnt lgkmcnt(0)" ::: "memory"); // deposits done
        __builtin_amdgcn_s_barrier();
#pragma unroll
        for (int u2 = 0; u2 < 8; u2++) {
            const int col = wid + 4 * u2;                  // wave owns full co row
            const float4 vv = *(const float4*)(obuf + col * 260 + lane * 4);
            const float4 xr = rv[nc & 1][u2];
            const size_t gbase = (size_t)(nc * 32 + col) * NPIX_L + px0 + lane * 4;
            float4 o;
            o.x = vv.x + xr.x; o.y = vv.y + xr.y;
            o.z = vv.z + xr.z; o.w = vv.w + xr.w;
            *(float4*)(ob + gbase) = o;
        }
        __builtin_amdgcn_s_barrier();                      // reads done before next deposit
    }
#undef STAGE
}

extern "C" void kernel_launch(void* const* d_in, const int* in_sizes, int n_in,
                              void* d_out, int out_size, void* d_ws, size_t ws_size,
                              hipStream_t stream) {
    const float* x_h  = (const float*)d_in[0];
    const float* x_l  = (const float*)d_in[1];
    const float* hg   = (const float*)d_in[2];
    const float* hb   = (const float*)d_in[3];
    const float* hm   = (const float*)d_in[4];
    const float* hv   = (const float*)d_in[5];
    const float* kvw  = (const float*)d_in[6];
    const float* kvb  = (const float*)d_in[7];
    const float* lg   = (const float*)d_in[8];
    const float* lb   = (const float*)d_in[9];
    const float* lm   = (const float*)d_in[10];
    const float* lv   = (const float*)d_in[11];
    const float* ratt = (const float*)d_in[12];
    float* ws  = (float*)d_ws;
    float* out = (float*)d_out;

    pool_bn_kernel<<<256, 256, 0, stream>>>(x_h, hg, hb, hm, hv, ws);
    kv_kernel<<<256, 256, 0, stream>>>(kvw, kvb, lg, lb, lm, lv, ratt, ws);
    attn_mfma<<<512, 256, 0, stream>>>(x_l, ws, out);
}